// Round 2
// baseline (604.983 us; speedup 1.0000x reference)
//
#include <hip/hip_runtime.h>
#include <hip/hip_bf16.h>

// Problem constants
#define BS 8
#define NN 64
#define HD 512
#define NLAYER 5
// Inputs fp32, output fp32 (128 MB). bf16 internally for MFMA.
// Big scratch lives in d_out (~74 MB of 128 MB); ws holds nodef + denom only
// (out_kernel reads nodef while rewriting d_out).

typedef short bf16x8 __attribute__((ext_vector_type(8)));
typedef float f32x4 __attribute__((ext_vector_type(4)));

__device__ __forceinline__ float lrelu(float x) { return x > 0.f ? x : 0.01f * x; }

__device__ __forceinline__ void cp16(const void* g, void* l) {
    __builtin_amdgcn_global_load_lds(
        (const __attribute__((address_space(1))) unsigned int*)g,
        (__attribute__((address_space(3))) unsigned int*)l,
        16, 0, 0);
}

// ---------------------------------------------------------------------------
// prep (fused wcvt + node init + edge_init + denom):
__global__ __launch_bounds__(256) void prep_kernel(
    const float* __restrict__ roi, const float* __restrict__ img,
    const float* __restrict__ nW, const float* __restrict__ eW,
    const int* __restrict__ mask,
    __hip_bfloat16* __restrict__ nWb, __hip_bfloat16* __restrict__ eWb,
    float* __restrict__ nodef, __hip_bfloat16* __restrict__ nodeb,
    float* __restrict__ edge_init, float* __restrict__ denom)
{
    int bid = blockIdx.x, tid = threadIdx.x;
    if (bid < 2560) {
        const float* src = (bid < 1280) ? nW : eW;
        __hip_bfloat16* dst = (bid < 1280) ? nWb : eWb;
        int base = ((bid < 1280) ? bid : bid - 1280) * 1024 + tid * 4;
#pragma unroll
        for (int k = 0; k < 4; ++k) dst[base + k] = __float2bfloat16(src[base + k]);
    } else if (bid < 2816) {
        int base = (bid - 2560) * 1024 + tid * 4;
#pragma unroll
        for (int k = 0; k < 4; ++k) {
            float v = roi[base + k];
            nodef[base + k] = v;
            nodeb[base + k] = __float2bfloat16(v);
        }
    } else if (bid < 3840) {
        int pid = (bid - 2816) * 4 + (tid >> 6);   // (b*512+h), 0..4095
        int l = tid & 63;
        const float* p = img + (size_t)pid * 196;
        float s = 0.f;
        for (int x = l; x < 196; x += 64) s += p[x];
#pragma unroll
        for (int off = 1; off < 64; off <<= 1) s += __shfl_xor(s, off, 64);
        if (l == 0) edge_init[pid] = s * (1.f / 196.f);
    } else {
        int pid = (bid - 3840) * 256 + tid;       // 0..511
        if (pid < 512) {
            const int* m = mask + pid * 64;
            int s = 0;
#pragma unroll
            for (int j = 0; j < 64; ++j) s += m[j];
            denom[pid] = (float)s + 1.f;
        }
    }
}

// ---------------------------------------------------------------------------
// em0: one wave per (b,o). Coalesced float4 loads of eW0 row, shuffle-reduce.
__global__ __launch_bounds__(256) void em0_kernel(
    const float* __restrict__ edge_init,
    const float* __restrict__ eW0,
    const float* __restrict__ eB0,
    float* __restrict__ em0)
{
    int W = blockIdx.x * 4 + (threadIdx.x >> 6);  // 0..4095
    int l = threadIdx.x & 63;
    int b = W >> 9, o = W & 511;
    const float4* ei = (const float4*)(edge_init + b * 512);
    const float4* w4 = (const float4*)(eW0 + (size_t)o * 512);
    float4 a0 = ei[l * 2], a1 = ei[l * 2 + 1];
    float4 b0 = w4[l * 2], b1 = w4[l * 2 + 1];
    float s = a0.x * b0.x + a0.y * b0.y + a0.z * b0.z + a0.w * b0.w
            + a1.x * b1.x + a1.y * b1.y + a1.z * b1.z + a1.w * b1.w;
#pragma unroll
    for (int off = 1; off < 64; off <<= 1) s += __shfl_xor(s, off, 64);
    if (l == 0) em0[W] = s + eB0[o];
}

// ---------------------------------------------------------------------------
// nm GEMM: nm[r][o] = sum_h node_bf16[r][h] * W[o][h] + bias[o]  (512x512x512)
// 2-phase double-buffered K-loop (BK=32): next-tile global_load_lds issued
// BEFORE current-tile ds_read+MFMA; single __syncthreads per K-step (its
// implicit vmcnt(0)/lgkmcnt(0) drain gives both the land guarantee and the
// WAR ordering). Only 64 blocks -> no cross-block latency cover, so the
// within-block overlap is the whole game here.
__global__ __launch_bounds__(256) void nm_gemm(
    const __hip_bfloat16* __restrict__ A,   // 512x512 node bf16
    const __hip_bfloat16* __restrict__ W,   // 512x512 (o,h) bf16
    const float* __restrict__ bias,
    float* __restrict__ nm)
{
    __shared__ __align__(16) __hip_bfloat16 sA[2][64 * 32];
    __shared__ __align__(16) __hip_bfloat16 sB[2][64 * 32];
    int tid = threadIdx.x;
    int bm = blockIdx.x, bn = blockIdx.y;
    int w = tid >> 6, l = tid & 63;
    int lq = l >> 4, lr = l & 15;

    const char* aBase = (const char*)A + (size_t)bm * 64 * 1024;  // row stride 1024B
    const char* bBase = (const char*)W + (size_t)bn * 64 * 1024;
    int r2 = tid >> 2;
    int offG = r2 * 1024 + ((((tid & 3) ^ (r2 & 3))) << 4);
    int offL = tid * 16;
    int sw = lr & 3;

    f32x4 acc[4] = {};

#define NM_STAGE(kt, bsel) do { \
        int ko = (kt) * 64; \
        cp16(aBase + offG + ko, (char*)sA[bsel] + offL); \
        cp16(bBase + offG + ko, (char*)sB[bsel] + offL); \
    } while (0)

#define NM_COMPUTE(bsel) do { \
        bf16x8 af = *(const bf16x8*)&sA[bsel][(w * 16 + lr) * 32 + ((lq ^ sw) << 3)]; \
        bf16x8 bfv[4]; \
        _Pragma("unroll") \
        for (int ni = 0; ni < 4; ++ni) \
            bfv[ni] = *(const bf16x8*)&sB[bsel][(ni * 16 + lr) * 32 + ((lq ^ sw) << 3)]; \
        __builtin_amdgcn_s_setprio(1); \
        _Pragma("unroll") \
        for (int ni = 0; ni < 4; ++ni) \
            acc[ni] = __builtin_amdgcn_mfma_f32_16x16x32_bf16(af, bfv[ni], acc[ni], 0, 0, 0); \
        __builtin_amdgcn_s_setprio(0); \
    } while (0)

    NM_STAGE(0, 0);
    __syncthreads();
#pragma unroll 2
    for (int kt = 0; kt < 15; ++kt) {
        NM_STAGE(kt + 1, (kt & 1) ^ 1);
        NM_COMPUTE(kt & 1);
        __syncthreads();
    }
    NM_COMPUTE(1);

#pragma unroll
    for (int ni = 0; ni < 4; ++ni) {
        int col = bn * 64 + ni * 16 + lr;
        float bv = bias[col];
#pragma unroll
        for (int r = 0; r < 4; ++r) {
            int row = bm * 64 + w * 16 + lq * 4 + r;
            nm[(size_t)row * 512 + col] = acc[ni][r] + bv;
        }
    }
#undef NM_STAGE
#undef NM_COMPUTE
}

// ---------------------------------------------------------------------------
// t=0: es = lrelu(nm_i + nm_j + em0_b), write es, agg -> fused node update
__global__ __launch_bounds__(256) void edge_rank1(
    const float* __restrict__ nm, const float* __restrict__ em0,
    const int* __restrict__ mask,
    __hip_bfloat16* __restrict__ es_dst,
    const float* __restrict__ denom,
    float* __restrict__ nodef, __hip_bfloat16* __restrict__ nodeb)
{
    int g = blockIdx.x >> 1, ch = blockIdx.x & 1;
    int w = threadIdx.x >> 6, l = threadIdx.x & 63;
    int c = ch * 256 + w * 64 + l;
    int b = g >> 6;
    float nmi = nm[(size_t)g * 512 + c];          // raw nm[g][c]
    float emb = em0[b * 512 + c];
    const float* nmb = nm + (size_t)b * 64 * 512;
    const int* mrow = mask + g * 64;
    __hip_bfloat16* erow = es_dst + (size_t)g * 64 * 512 + c;
    float aggv = 0.f;
#pragma unroll 4
    for (int j = 0; j < 64; ++j) {
        float nmj = nmb[j * 512 + c];
        float es = lrelu(nmi + nmj + emb);
        erow[(size_t)j * 512] = __float2bfloat16(es);
        aggv += es * nmj * (float)mrow[j];
    }
    // fused node update (thread owns (g,c))
    float nf = (nmi + aggv) / denom[g];
    size_t idx = (size_t)g * 512 + c;
    float ns = nodef[idx] + lrelu(nf);
    nodef[idx] = ns;
    nodeb[idx] = __float2bfloat16(ns);
}

// ---------------------------------------------------------------------------
// Fused edge GEMM + epilogue + node update for t>=1.  BM=BN=128, BK=32.
// 2-phase double-buffered K-loop: LDS 2x(8+8) KB = 32 KB total (same
// footprint as the old single-buffered BK=64 -> occupancy preserved, m132
// trap avoided). Next-tile stage issued before current-tile compute; one
// barrier per K-step. setprio(1) around the MFMA cluster.
__global__ __launch_bounds__(256) void edge_fused(
    const __hip_bfloat16* __restrict__ es_src,   // 32768 x 512 bf16
    const __hip_bfloat16* __restrict__ eW,       // 512 x 512 bf16 (o,h)
    const float* __restrict__ eB,                // 512 fp32
    const float* __restrict__ nm,                // 512 x 512 fp32
    const int* __restrict__ mask,                // 8*64*64
    __hip_bfloat16* __restrict__ es_dst,
    const float* __restrict__ denom,
    float* __restrict__ nodef, __hip_bfloat16* __restrict__ nodeb,
    int write_es)
{
    __shared__ __align__(16) __hip_bfloat16 sA[2][128 * 32];   // 8 KB each
    __shared__ __align__(16) __hip_bfloat16 sB[2][128 * 32];   // 8 KB each
    int tid = threadIdx.x;
    // XCD swizzle: lid%8 = XCD (8 XCDs, 1024 blocks). Make bm a function of
    // lid%8 so the 4 bn-siblings (same A-tile) land on the same XCD.
    int lid = blockIdx.y * 4 + blockIdx.x;
    int xcd = lid & 7, idx = lid >> 3;
    int bm = xcd + ((idx >> 2) << 3);            // 0..255
    int bn = idx & 3;                            // 0..3
    int w = tid >> 6, l = tid & 63;
    int wm = w >> 1, wn = w & 1;
    int lq = l >> 4, lr = l & 15;

    const char* aBase = (const char*)es_src + (size_t)bm * 128 * 1024;  // row 1024B
    const char* bBase = (const char*)eW + (size_t)bn * 128 * 1024;
    // staging geometry per K-tile (32 cols = 64 B/row): A tile = 128 rows x
    // 64 B = 512 chunks of 16 B; thread t stages chunks t and t+256.
    // chunk c: row = c>>2, c16 = c&3; source column pre-swizzled
    // (c16 ^ row&3), LDS dest linear (rule #21).
    int r0 = tid >> 2, c16 = tid & 3;
    int g0 = r0 * 1024 + (((c16 ^ (r0 & 3))) << 4);
    int l0 = tid * 16;
    int swr = lr & 3;

    f32x4 acc[4][4] = {};

#define EF_STAGE(kt, bsel) do { \
        int ko = (kt) * 64; \
        cp16(aBase + g0 + ko,         (char*)sA[bsel] + l0); \
        cp16(aBase + g0 + 65536 + ko, (char*)sA[bsel] + l0 + 4096); \
        cp16(bBase + g0 + ko,         (char*)sB[bsel] + l0); \
        cp16(bBase + g0 + 65536 + ko, (char*)sB[bsel] + l0 + 4096); \
    } while (0)

#define EF_COMPUTE(bsel) do { \
        bf16x8 af[4], bfv[4]; \
        _Pragma("unroll") \
        for (int mi = 0; mi < 4; ++mi) \
            af[mi] = *(const bf16x8*)&sA[bsel][(wm * 64 + mi * 16 + lr) * 32 + ((lq ^ swr) << 3)]; \
        _Pragma("unroll") \
        for (int ni = 0; ni < 4; ++ni) \
            bfv[ni] = *(const bf16x8*)&sB[bsel][(wn * 64 + ni * 16 + lr) * 32 + ((lq ^ swr) << 3)]; \
        __builtin_amdgcn_s_setprio(1); \
        _Pragma("unroll") \
        for (int mi = 0; mi < 4; ++mi) \
            _Pragma("unroll") \
            for (int ni = 0; ni < 4; ++ni) \
                acc[mi][ni] = __builtin_amdgcn_mfma_f32_16x16x32_bf16(af[mi], bfv[ni], acc[mi][ni], 0, 0, 0); \
        __builtin_amdgcn_s_setprio(0); \
    } while (0)

    EF_STAGE(0, 0);
    __syncthreads();
#pragma unroll 2
    for (int kt = 0; kt < 15; ++kt) {
        EF_STAGE(kt + 1, (kt & 1) ^ 1);   // into the buffer freed last iter
        EF_COMPUTE(kt & 1);
        __syncthreads();                  // vmcnt(0)+lgkmcnt(0)+barrier
    }

    // Epilogue operand prefetch — issue before the last MFMA cluster so the
    // global-load latency hides under it.
    int g = bm * 2 + wm;            // = b*64 + i
    int b = g >> 6;
    int cbase = bn * 128 + wn * 64;
    float nmraw[4], nmi[4];
#pragma unroll
    for (int ni = 0; ni < 4; ++ni) {
        int c = cbase + ni * 16 + lr;
        nmraw[ni] = nm[(size_t)g * 512 + c];
        nmi[ni] = nmraw[ni] + eB[c];
    }
    float dinv = denom[g];
    const float* nmb = nm + (size_t)b * 64 * 512;
    const int* mrow = mask + g * 64;

    EF_COMPUTE(1);                        // kt = 15 lives in buffer 1

    float aggv[4] = {0.f, 0.f, 0.f, 0.f};
#pragma unroll
    for (int mi = 0; mi < 4; ++mi) {
#pragma unroll
        for (int r = 0; r < 4; ++r) {
            int j = mi * 16 + lq * 4 + r;
            float mf = (float)mrow[j];
            const float* nrow = nmb + (size_t)j * 512;
            size_t erow = ((size_t)(g * 64 + j)) * 512;
#pragma unroll
            for (int ni = 0; ni < 4; ++ni) {
                int c = cbase + ni * 16 + lr;
                float nmj = nrow[c];
                float es = lrelu(acc[mi][ni][r] + nmi[ni] + nmj);
                if (write_es) es_dst[erow + c] = __float2bfloat16(es);
                aggv[ni] += es * nmj * mf;
            }
        }
    }
#pragma unroll
    for (int ni = 0; ni < 4; ++ni) {
        float v = aggv[ni];
        v += __shfl_xor(v, 16, 64);
        v += __shfl_xor(v, 32, 64);
        if (lq == 0) {
            size_t oidx = (size_t)g * 512 + cbase + ni * 16 + lr;
            float nf = (nmraw[ni] + v) / dinv;
            float ns = nodef[oidx] + lrelu(nf);
            nodef[oidx] = ns;
            nodeb[oidx] = __float2bfloat16(ns);
        }
    }
#undef EF_STAGE
#undef EF_COMPUTE
}

// ---------------------------------------------------------------------------
// out (fp32): out[b,i,j,0:512]=node[b,i,:], [512:1024]=node[b,j,:]
__global__ __launch_bounds__(256) void out_kernel(
    const float* __restrict__ nodef, float* __restrict__ out)
{
    size_t ch = (size_t)blockIdx.x * 256 + threadIdx.x;  // 16B chunk id
    int c4 = (int)(ch & 255);          // 256 chunks per 1024-float row
    size_t r = ch >> 8;                // (b*64+i)*64 + j
    int b = (int)(r >> 12);
    int i = (int)((r >> 6) & 63);
    int j = (int)(r & 63);
    int c = c4 * 4;
    const float* src = (c < 512) ? (nodef + ((size_t)(b * 64 + i)) * 512 + c)
                                 : (nodef + ((size_t)(b * 64 + j)) * 512 + (c - 512));
    *reinterpret_cast<float4*>(out + ch * 4) = *reinterpret_cast<const float4*>(src);
}

// ---------------------------------------------------------------------------
extern "C" void kernel_launch(void* const* d_in, const int* in_sizes, int n_in,
                              void* d_out, int out_size, void* d_ws, size_t ws_size,
                              hipStream_t stream) {
    const float* roi  = (const float*)d_in[0];
    const float* img  = (const float*)d_in[1];
    const float* nW   = (const float*)d_in[2];
    const float* nB   = (const float*)d_in[3];
    const float* eW   = (const float*)d_in[4];
    const float* eB   = (const float*)d_in[5];
    const int*   mask = (const int*)d_in[6];

    // Large scratch inside d_out (128 MB); all dead before out_kernel rewrites.
    char* ob = (char*)d_out;
    const size_t ES_BYTES = (size_t)32768 * 512 * 2;            // 33,554,432
    __hip_bfloat16* es0   = (__hip_bfloat16*)(ob);
    __hip_bfloat16* es1   = (__hip_bfloat16*)(ob + ES_BYTES);
    __hip_bfloat16* eWb   = (__hip_bfloat16*)(ob + 2 * ES_BYTES);              // 2.62MB
    __hip_bfloat16* nWb   = (__hip_bfloat16*)(ob + 2 * ES_BYTES + 2621440);    // 2.62MB
    __hip_bfloat16* nodeb = (__hip_bfloat16*)(ob + 2 * ES_BYTES + 5242880);    // 0.5MB
    float*          nm    = (float*)(ob + 2 * ES_BYTES + 5767168);             // 1MB
    float*       edge_init= (float*)(ob + 2 * ES_BYTES + 6815744);             // 16KB
    float*          em0   = (float*)(ob + 2 * ES_BYTES + 6832128);             // 16KB

    char* ws = (char*)d_ws;
    float* nodef = (float*)(ws);                 // 1MB
    float* denom = (float*)(ws + 1048576);       // 2KB
    float* outp  = (float*)d_out;

    prep_kernel<<<3842, 256, 0, stream>>>(roi, img, nW, eW, mask,
                                          nWb, eWb, nodef, nodeb, edge_init, denom);
    em0_kernel<<<1024, 256, 0, stream>>>(edge_init, eW, eB, em0);

    // t = 0
    nm_gemm<<<dim3(8, 8), 256, 0, stream>>>(nodeb, nWb, nB, nm);
    edge_rank1<<<1024, 256, 0, stream>>>(nm, em0, mask, es0, denom, nodef, nodeb);

    // t = 1..4
    for (int t = 1; t < NLAYER; ++t) {
        const __hip_bfloat16* src = (t & 1) ? es0 : es1;
        __hip_bfloat16* dst       = (t & 1) ? es1 : es0;
        nm_gemm<<<dim3(8, 8), 256, 0, stream>>>(nodeb, nWb + (size_t)t * 262144,
                                                nB + t * 512, nm);
        edge_fused<<<dim3(4, 256), 256, 0, stream>>>(src, eWb + (size_t)t * 262144,
                                                     eB + t * 512, nm, mask,
                                                     dst, denom, nodef, nodeb,
                                                     (t < 4) ? 1 : 0);
    }

    out_kernel<<<32768, 256, 0, stream>>>(nodef, outp);
}

// Round 3
// 581.053 us; speedup vs baseline: 1.0412x; 1.0412x over previous
//
#include <hip/hip_runtime.h>
#include <hip/hip_bf16.h>

// Problem constants
#define BS 8
#define NN 64
#define HD 512
#define NLAYER 5
// Inputs fp32, output fp32 (128 MB). bf16 internally for MFMA.
// Big scratch lives in d_out (~74 MB of 128 MB); ws holds nodef + denom only
// (out_kernel reads nodef while rewriting d_out).

typedef short bf16x8 __attribute__((ext_vector_type(8)));
typedef float f32x4 __attribute__((ext_vector_type(4)));

__device__ __forceinline__ float lrelu(float x) { return x > 0.f ? x : 0.01f * x; }

__device__ __forceinline__ void cp16(const void* g, void* l) {
    __builtin_amdgcn_global_load_lds(
        (const __attribute__((address_space(1))) unsigned int*)g,
        (__attribute__((address_space(3))) unsigned int*)l,
        16, 0, 0);
}

// Counted waits (T4): never drain vmcnt to 0 in the main loop.
#define WAITVM(N) do { \
        asm volatile("s_waitcnt vmcnt(" #N ")" ::: "memory"); \
        __builtin_amdgcn_sched_barrier(0); \
    } while (0)

// ---------------------------------------------------------------------------
// prep (fused wcvt + node init + edge_init + denom):
__global__ __launch_bounds__(256) void prep_kernel(
    const float* __restrict__ roi, const float* __restrict__ img,
    const float* __restrict__ nW, const float* __restrict__ eW,
    const int* __restrict__ mask,
    __hip_bfloat16* __restrict__ nWb, __hip_bfloat16* __restrict__ eWb,
    float* __restrict__ nodef, __hip_bfloat16* __restrict__ nodeb,
    float* __restrict__ edge_init, float* __restrict__ denom)
{
    int bid = blockIdx.x, tid = threadIdx.x;
    if (bid < 2560) {
        const float* src = (bid < 1280) ? nW : eW;
        __hip_bfloat16* dst = (bid < 1280) ? nWb : eWb;
        int base = ((bid < 1280) ? bid : bid - 1280) * 1024 + tid * 4;
#pragma unroll
        for (int k = 0; k < 4; ++k) dst[base + k] = __float2bfloat16(src[base + k]);
    } else if (bid < 2816) {
        int base = (bid - 2560) * 1024 + tid * 4;
#pragma unroll
        for (int k = 0; k < 4; ++k) {
            float v = roi[base + k];
            nodef[base + k] = v;
            nodeb[base + k] = __float2bfloat16(v);
        }
    } else if (bid < 3840) {
        int pid = (bid - 2816) * 4 + (tid >> 6);   // (b*512+h), 0..4095
        int l = tid & 63;
        const float* p = img + (size_t)pid * 196;
        float s = 0.f;
        for (int x = l; x < 196; x += 64) s += p[x];
#pragma unroll
        for (int off = 1; off < 64; off <<= 1) s += __shfl_xor(s, off, 64);
        if (l == 0) edge_init[pid] = s * (1.f / 196.f);
    } else {
        int pid = (bid - 3840) * 256 + tid;       // 0..511
        if (pid < 512) {
            const int* m = mask + pid * 64;
            int s = 0;
#pragma unroll
            for (int j = 0; j < 64; ++j) s += m[j];
            denom[pid] = (float)s + 1.f;
        }
    }
}

// ---------------------------------------------------------------------------
// em0: one wave per (b,o). Coalesced float4 loads of eW0 row, shuffle-reduce.
__global__ __launch_bounds__(256) void em0_kernel(
    const float* __restrict__ edge_init,
    const float* __restrict__ eW0,
    const float* __restrict__ eB0,
    float* __restrict__ em0)
{
    int W = blockIdx.x * 4 + (threadIdx.x >> 6);  // 0..4095
    int l = threadIdx.x & 63;
    int b = W >> 9, o = W & 511;
    const float4* ei = (const float4*)(edge_init + b * 512);
    const float4* w4 = (const float4*)(eW0 + (size_t)o * 512);
    float4 a0 = ei[l * 2], a1 = ei[l * 2 + 1];
    float4 b0 = w4[l * 2], b1 = w4[l * 2 + 1];
    float s = a0.x * b0.x + a0.y * b0.y + a0.z * b0.z + a0.w * b0.w
            + a1.x * b1.x + a1.y * b1.y + a1.z * b1.z + a1.w * b1.w;
#pragma unroll
    for (int off = 1; off < 64; off <<= 1) s += __shfl_xor(s, off, 64);
    if (l == 0) em0[W] = s + eB0[o];
}

// ---------------------------------------------------------------------------
// nm GEMM: nm[r][o] = sum_h node_bf16[r][h] * W[o][h] + bias[o]  (512x512x512)
// Counted-vmcnt double-buffered pipeline (T3/T4 minimum): 16 K-tiles of
// BK=32; 2 LDS buffers; raw s_barrier; steady-state wait = vmcnt(2)
// (each wave's stage = 2 global_load_lds). Next-next tile's loads stay in
// flight ACROSS the barrier — no full drain until the last tile.
__global__ __launch_bounds__(256) void nm_gemm(
    const __hip_bfloat16* __restrict__ A,   // 512x512 node bf16
    const __hip_bfloat16* __restrict__ W,   // 512x512 (o,h) bf16
    const float* __restrict__ bias,
    float* __restrict__ nm)
{
    __shared__ __align__(16) __hip_bfloat16 sA[2][64 * 32];
    __shared__ __align__(16) __hip_bfloat16 sB[2][64 * 32];
    int tid = threadIdx.x;
    int bm = blockIdx.x, bn = blockIdx.y;
    int w = tid >> 6, l = tid & 63;
    int lq = l >> 4, lr = l & 15;

    const char* aBase = (const char*)A + (size_t)bm * 64 * 1024;  // row stride 1024B
    const char* bBase = (const char*)W + (size_t)bn * 64 * 1024;
    int r2 = tid >> 2;
    int offG = r2 * 1024 + ((((tid & 3) ^ (r2 & 3))) << 4);
    int offL = tid * 16;
    int sw = lr & 3;

    f32x4 acc[4] = {};

#define NM_STAGE(kt, bsel) do { \
        int ko = (kt) * 64; \
        cp16(aBase + offG + ko, (char*)sA[bsel] + offL); \
        cp16(bBase + offG + ko, (char*)sB[bsel] + offL); \
    } while (0)

#define NM_COMPUTE(bsel) do { \
        bf16x8 af = *(const bf16x8*)&sA[bsel][(w * 16 + lr) * 32 + ((lq ^ sw) << 3)]; \
        bf16x8 bfv[4]; \
        _Pragma("unroll") \
        for (int ni = 0; ni < 4; ++ni) \
            bfv[ni] = *(const bf16x8*)&sB[bsel][(ni * 16 + lr) * 32 + ((lq ^ sw) << 3)]; \
        __builtin_amdgcn_s_setprio(1); \
        _Pragma("unroll") \
        for (int ni = 0; ni < 4; ++ni) \
            acc[ni] = __builtin_amdgcn_mfma_f32_16x16x32_bf16(af, bfv[ni], acc[ni], 0, 0, 0); \
        __builtin_amdgcn_s_setprio(0); \
    } while (0)

    NM_STAGE(0, 0);
    NM_STAGE(1, 1);
#pragma unroll
    for (int kt = 0; kt < 14; ++kt) {
        WAITVM(2);                        // tile kt's 2 loads landed (per wave)
        __builtin_amdgcn_s_barrier();     // block-wide: buffer kt&1 ready
        NM_COMPUTE(kt & 1);
        __builtin_amdgcn_s_barrier();     // all reads of buffer kt&1 done
        NM_STAGE(kt + 2, kt & 1);         // overwrite it; stays in flight
    }
    WAITVM(2);
    __builtin_amdgcn_s_barrier();
    NM_COMPUTE(0);                        // tile 14
    WAITVM(0);
    __builtin_amdgcn_s_barrier();
    NM_COMPUTE(1);                        // tile 15

#pragma unroll
    for (int ni = 0; ni < 4; ++ni) {
        int col = bn * 64 + ni * 16 + lr;
        float bv = bias[col];
#pragma unroll
        for (int r = 0; r < 4; ++r) {
            int row = bm * 64 + w * 16 + lq * 4 + r;
            nm[(size_t)row * 512 + col] = acc[ni][r] + bv;
        }
    }
#undef NM_STAGE
#undef NM_COMPUTE
}

// ---------------------------------------------------------------------------
// t=0: es = lrelu(nm_i + nm_j + em0_b), write es, agg -> fused node update
__global__ __launch_bounds__(256) void edge_rank1(
    const float* __restrict__ nm, const float* __restrict__ em0,
    const int* __restrict__ mask,
    __hip_bfloat16* __restrict__ es_dst,
    const float* __restrict__ denom,
    float* __restrict__ nodef, __hip_bfloat16* __restrict__ nodeb)
{
    int g = blockIdx.x >> 1, ch = blockIdx.x & 1;
    int w = threadIdx.x >> 6, l = threadIdx.x & 63;
    int c = ch * 256 + w * 64 + l;
    int b = g >> 6;
    float nmi = nm[(size_t)g * 512 + c];          // raw nm[g][c]
    float emb = em0[b * 512 + c];
    const float* nmb = nm + (size_t)b * 64 * 512;
    const int* mrow = mask + g * 64;
    __hip_bfloat16* erow = es_dst + (size_t)g * 64 * 512 + c;
    float aggv = 0.f;
#pragma unroll 4
    for (int j = 0; j < 64; ++j) {
        float nmj = nmb[j * 512 + c];
        float es = lrelu(nmi + nmj + emb);
        erow[(size_t)j * 512] = __float2bfloat16(es);
        aggv += es * nmj * (float)mrow[j];
    }
    // fused node update (thread owns (g,c))
    float nf = (nmi + aggv) / denom[g];
    size_t idx = (size_t)g * 512 + c;
    float ns = nodef[idx] + lrelu(nf);
    nodef[idx] = ns;
    nodeb[idx] = __float2bfloat16(ns);
}

// ---------------------------------------------------------------------------
// Fused edge GEMM + epilogue + node update for t>=1.  BM=BN=128, BK=64.
// Counted-vmcnt double-buffered pipeline: 8 K-tiles, 2 LDS buffers
// (2x32 KB = 64 KB -> 2 blocks/CU), raw s_barrier, steady-state wait =
// vmcnt(8) (per-wave stage = 8 global_load_lds). The next tile's loads
// remain in flight across the barrier instead of being drained by
// __syncthreads' implicit vmcnt(0) — that drain was the round-2 regression
// and the round-0/1 hidden stall (MfmaUtil 6.3%, 85% idle).
__global__ __launch_bounds__(256) void edge_fused(
    const __hip_bfloat16* __restrict__ es_src,   // 32768 x 512 bf16
    const __hip_bfloat16* __restrict__ eW,       // 512 x 512 bf16 (o,h)
    const float* __restrict__ eB,                // 512 fp32
    const float* __restrict__ nm,                // 512 x 512 fp32
    const int* __restrict__ mask,                // 8*64*64
    __hip_bfloat16* __restrict__ es_dst,
    const float* __restrict__ denom,
    float* __restrict__ nodef, __hip_bfloat16* __restrict__ nodeb,
    int write_es)
{
    __shared__ __align__(16) __hip_bfloat16 sA[2][128 * 64];   // 16 KB each
    __shared__ __align__(16) __hip_bfloat16 sB[2][128 * 64];   // 16 KB each
    int tid = threadIdx.x;
    // XCD swizzle: lid%8 = XCD (8 XCDs, 1024 blocks). Make bm a function of
    // lid%8 so the 4 bn-siblings (same A-tile) land on the same XCD.
    int lid = blockIdx.y * 4 + blockIdx.x;
    int xcd = lid & 7, idx = lid >> 3;
    int bm = xcd + ((idx >> 2) << 3);            // 0..255
    int bn = idx & 3;                            // 0..3
    int w = tid >> 6, l = tid & 63;
    int wm = w >> 1, wn = w & 1;
    int lq = l >> 4, lr = l & 15;

    const char* aBase = (const char*)es_src + (size_t)bm * 128 * 1024;  // row 1024B
    const char* bBase = (const char*)eW + (size_t)bn * 128 * 1024;
    // staging: physical LDS chunk = tid + i*256 -> (row = tid>>3 + i*32,
    // c16 = tid&7).  Source column pre-swizzled: logical c16 = (tid&7)^(row&7);
    // LDS dest linear (rule #21); read applies same XOR.
    int rrow = tid >> 3;
    int gOff = rrow * 1024 + ((((tid & 7) ^ (rrow & 7))) << 4);
    int lOff = tid * 16;
    int sw = lr & 7;

    f32x4 acc[4][4] = {};

#define EF_STAGE(kt, bsel) do { \
        int ko = (kt) * 128; \
        _Pragma("unroll") \
        for (int i = 0; i < 4; ++i) { \
            cp16(aBase + gOff + i * 32768 + ko, (char*)sA[bsel] + lOff + i * 4096); \
            cp16(bBase + gOff + i * 32768 + ko, (char*)sB[bsel] + lOff + i * 4096); \
        } \
    } while (0)

#define EF_COMPUTE(bsel) do { \
        _Pragma("unroll") \
        for (int kk = 0; kk < 2; ++kk) { \
            bf16x8 af[4], bfv[4]; \
            _Pragma("unroll") \
            for (int mi = 0; mi < 4; ++mi) \
                af[mi] = *(const bf16x8*)&sA[bsel][(wm * 64 + mi * 16 + lr) * 64 + (((kk * 4 + lq) ^ sw) << 3)]; \
            _Pragma("unroll") \
            for (int ni = 0; ni < 4; ++ni) \
                bfv[ni] = *(const bf16x8*)&sB[bsel][(wn * 64 + ni * 16 + lr) * 64 + (((kk * 4 + lq) ^ sw) << 3)]; \
            __builtin_amdgcn_s_setprio(1); \
            _Pragma("unroll") \
            for (int mi = 0; mi < 4; ++mi) \
                _Pragma("unroll") \
                for (int ni = 0; ni < 4; ++ni) \
                    acc[mi][ni] = __builtin_amdgcn_mfma_f32_16x16x32_bf16(af[mi], bfv[ni], acc[mi][ni], 0, 0, 0); \
            __builtin_amdgcn_s_setprio(0); \
        } \
    } while (0)

    EF_STAGE(0, 0);
    EF_STAGE(1, 1);
#pragma unroll
    for (int kt = 0; kt < 6; ++kt) {
        WAITVM(8);                        // tile kt's 8 loads landed (per wave)
        __builtin_amdgcn_s_barrier();     // block-wide: buffer kt&1 ready
        EF_COMPUTE(kt & 1);
        __builtin_amdgcn_s_barrier();     // all reads of buffer kt&1 done
        EF_STAGE(kt + 2, kt & 1);         // overwrite; stays in flight
    }
    WAITVM(8);
    __builtin_amdgcn_s_barrier();
    EF_COMPUTE(0);                        // tile 6

    // Epilogue operand prefetch — hide under the last MFMA cluster.
    int g = bm * 2 + wm;            // = b*64 + i
    int b = g >> 6;
    int cbase = bn * 128 + wn * 64;
    float nmraw[4], nmi[4];
#pragma unroll
    for (int ni = 0; ni < 4; ++ni) {
        int c = cbase + ni * 16 + lr;
        nmraw[ni] = nm[(size_t)g * 512 + c];
        nmi[ni] = nmraw[ni] + eB[c];
    }
    float dinv = denom[g];
    const float* nmb = nm + (size_t)b * 64 * 512;
    const int* mrow = mask + g * 64;

    WAITVM(0);                            // tile 7's loads (epilogue loads use
    __builtin_amdgcn_s_barrier();         // vgpr results, ordered by data dep)
    EF_COMPUTE(1);                        // tile 7

    float aggv[4] = {0.f, 0.f, 0.f, 0.f};
#pragma unroll
    for (int mi = 0; mi < 4; ++mi) {
#pragma unroll
        for (int r = 0; r < 4; ++r) {
            int j = mi * 16 + lq * 4 + r;
            float mf = (float)mrow[j];
            const float* nrow = nmb + (size_t)j * 512;
            size_t erow = ((size_t)(g * 64 + j)) * 512;
#pragma unroll
            for (int ni = 0; ni < 4; ++ni) {
                int c = cbase + ni * 16 + lr;
                float nmj = nrow[c];
                float es = lrelu(acc[mi][ni][r] + nmi[ni] + nmj);
                if (write_es) es_dst[erow + c] = __float2bfloat16(es);
                aggv[ni] += es * nmj * mf;
            }
        }
    }
#pragma unroll
    for (int ni = 0; ni < 4; ++ni) {
        float v = aggv[ni];
        v += __shfl_xor(v, 16, 64);
        v += __shfl_xor(v, 32, 64);
        if (lq == 0) {
            size_t oidx = (size_t)g * 512 + cbase + ni * 16 + lr;
            float nf = (nmraw[ni] + v) / dinv;
            float ns = nodef[oidx] + lrelu(nf);
            nodef[oidx] = ns;
            nodeb[oidx] = __float2bfloat16(ns);
        }
    }
#undef EF_STAGE
#undef EF_COMPUTE
}

// ---------------------------------------------------------------------------
// out (fp32): out[b,i,j,0:512]=node[b,i,:], [512:1024]=node[b,j,:]
__global__ __launch_bounds__(256) void out_kernel(
    const float* __restrict__ nodef, float* __restrict__ out)
{
    size_t ch = (size_t)blockIdx.x * 256 + threadIdx.x;  // 16B chunk id
    int c4 = (int)(ch & 255);          // 256 chunks per 1024-float row
    size_t r = ch >> 8;                // (b*64+i)*64 + j
    int b = (int)(r >> 12);
    int i = (int)((r >> 6) & 63);
    int j = (int)(r & 63);
    int c = c4 * 4;
    const float* src = (c < 512) ? (nodef + ((size_t)(b * 64 + i)) * 512 + c)
                                 : (nodef + ((size_t)(b * 64 + j)) * 512 + (c - 512));
    *reinterpret_cast<float4*>(out + ch * 4) = *reinterpret_cast<const float4*>(src);
}

// ---------------------------------------------------------------------------
extern "C" void kernel_launch(void* const* d_in, const int* in_sizes, int n_in,
                              void* d_out, int out_size, void* d_ws, size_t ws_size,
                              hipStream_t stream) {
    const float* roi  = (const float*)d_in[0];
    const float* img  = (const float*)d_in[1];
    const float* nW   = (const float*)d_in[2];
    const float* nB   = (const float*)d_in[3];
    const float* eW   = (const float*)d_in[4];
    const float* eB   = (const float*)d_in[5];
    const int*   mask = (const int*)d_in[6];

    // Large scratch inside d_out (128 MB); all dead before out_kernel rewrites.
    char* ob = (char*)d_out;
    const size_t ES_BYTES = (size_t)32768 * 512 * 2;            // 33,554,432
    __hip_bfloat16* es0   = (__hip_bfloat16*)(ob);
    __hip_bfloat16* es1   = (__hip_bfloat16*)(ob + ES_BYTES);
    __hip_bfloat16* eWb   = (__hip_bfloat16*)(ob + 2 * ES_BYTES);              // 2.62MB
    __hip_bfloat16* nWb   = (__hip_bfloat16*)(ob + 2 * ES_BYTES + 2621440);    // 2.62MB
    __hip_bfloat16* nodeb = (__hip_bfloat16*)(ob + 2 * ES_BYTES + 5242880);    // 0.5MB
    float*          nm    = (float*)(ob + 2 * ES_BYTES + 5767168);             // 1MB
    float*       edge_init= (float*)(ob + 2 * ES_BYTES + 6815744);             // 16KB
    float*          em0   = (float*)(ob + 2 * ES_BYTES + 6832128);             // 16KB

    char* ws = (char*)d_ws;
    float* nodef = (float*)(ws);                 // 1MB
    float* denom = (float*)(ws + 1048576);       // 2KB
    float* outp  = (float*)d_out;

    prep_kernel<<<3842, 256, 0, stream>>>(roi, img, nW, eW, mask,
                                          nWb, eWb, nodef, nodeb, edge_init, denom);
    em0_kernel<<<1024, 256, 0, stream>>>(edge_init, eW, eB, em0);

    // t = 0
    nm_gemm<<<dim3(8, 8), 256, 0, stream>>>(nodeb, nWb, nB, nm);
    edge_rank1<<<1024, 256, 0, stream>>>(nm, em0, mask, es0, denom, nodef, nodeb);

    // t = 1..4
    for (int t = 1; t < NLAYER; ++t) {
        const __hip_bfloat16* src = (t & 1) ? es0 : es1;
        __hip_bfloat16* dst       = (t & 1) ? es1 : es0;
        nm_gemm<<<dim3(8, 8), 256, 0, stream>>>(nodeb, nWb + (size_t)t * 262144,
                                                nB + t * 512, nm);
        edge_fused<<<dim3(4, 256), 256, 0, stream>>>(src, eWb + (size_t)t * 262144,
                                                     eB + t * 512, nm, mask,
                                                     dst, denom, nodef, nodeb,
                                                     (t < 4) ? 1 : 0);
    }

    out_kernel<<<32768, 256, 0, stream>>>(nodef, outp);
}

// Round 4
// 400.837 us; speedup vs baseline: 1.5093x; 1.4496x over previous
//
#include <hip/hip_runtime.h>
#include <hip/hip_bf16.h>

// Problem constants
#define BS 8
#define NN 64
#define HD 512
#define NLAYER 5
// Inputs fp32, output fp32 (128 MB). bf16 internally for MFMA.
// Big scratch lives in d_out (~74 MB of 128 MB); ws holds nodef + denom only
// (out_kernel reads nodef while rewriting d_out).

typedef short bf16x8 __attribute__((ext_vector_type(8)));
typedef float f32x4 __attribute__((ext_vector_type(4)));

__device__ __forceinline__ float lrelu(float x) { return x > 0.f ? x : 0.01f * x; }

__device__ __forceinline__ void cp16(const void* g, void* l) {
    __builtin_amdgcn_global_load_lds(
        (const __attribute__((address_space(1))) unsigned int*)g,
        (__attribute__((address_space(3))) unsigned int*)l,
        16, 0, 0);
}

// ---------------------------------------------------------------------------
// prep (fused wcvt + node init + edge_init + denom):
__global__ __launch_bounds__(256) void prep_kernel(
    const float* __restrict__ roi, const float* __restrict__ img,
    const float* __restrict__ nW, const float* __restrict__ eW,
    const int* __restrict__ mask,
    __hip_bfloat16* __restrict__ nWb, __hip_bfloat16* __restrict__ eWb,
    float* __restrict__ nodef, __hip_bfloat16* __restrict__ nodeb,
    float* __restrict__ edge_init, float* __restrict__ denom)
{
    int bid = blockIdx.x, tid = threadIdx.x;
    if (bid < 2560) {
        const float* src = (bid < 1280) ? nW : eW;
        __hip_bfloat16* dst = (bid < 1280) ? nWb : eWb;
        int base = ((bid < 1280) ? bid : bid - 1280) * 1024 + tid * 4;
#pragma unroll
        for (int k = 0; k < 4; ++k) dst[base + k] = __float2bfloat16(src[base + k]);
    } else if (bid < 2816) {
        int base = (bid - 2560) * 1024 + tid * 4;
#pragma unroll
        for (int k = 0; k < 4; ++k) {
            float v = roi[base + k];
            nodef[base + k] = v;
            nodeb[base + k] = __float2bfloat16(v);
        }
    } else if (bid < 3840) {
        int pid = (bid - 2816) * 4 + (tid >> 6);   // (b*512+h), 0..4095
        int l = tid & 63;
        const float* p = img + (size_t)pid * 196;
        float s = 0.f;
        for (int x = l; x < 196; x += 64) s += p[x];
#pragma unroll
        for (int off = 1; off < 64; off <<= 1) s += __shfl_xor(s, off, 64);
        if (l == 0) edge_init[pid] = s * (1.f / 196.f);
    } else {
        int pid = (bid - 3840) * 256 + tid;       // 0..511
        if (pid < 512) {
            const int* m = mask + pid * 64;
            int s = 0;
#pragma unroll
            for (int j = 0; j < 64; ++j) s += m[j];
            denom[pid] = (float)s + 1.f;
        }
    }
}

// ---------------------------------------------------------------------------
// em0: one wave per (b,o). Coalesced float4 loads of eW0 row, shuffle-reduce.
__global__ __launch_bounds__(256) void em0_kernel(
    const float* __restrict__ edge_init,
    const float* __restrict__ eW0,
    const float* __restrict__ eB0,
    float* __restrict__ em0)
{
    int W = blockIdx.x * 4 + (threadIdx.x >> 6);  // 0..4095
    int l = threadIdx.x & 63;
    int b = W >> 9, o = W & 511;
    const float4* ei = (const float4*)(edge_init + b * 512);
    const float4* w4 = (const float4*)(eW0 + (size_t)o * 512);
    float4 a0 = ei[l * 2], a1 = ei[l * 2 + 1];
    float4 b0 = w4[l * 2], b1 = w4[l * 2 + 1];
    float s = a0.x * b0.x + a0.y * b0.y + a0.z * b0.z + a0.w * b0.w
            + a1.x * b1.x + a1.y * b1.y + a1.z * b1.z + a1.w * b1.w;
#pragma unroll
    for (int off = 1; off < 64; off <<= 1) s += __shfl_xor(s, off, 64);
    if (l == 0) em0[W] = s + eB0[o];
}

// ---------------------------------------------------------------------------
// nm GEMM: nm[r][o] = sum_h node_bf16[r][h] * W[o][h] + bias[o]  (512x512x512)
// Regridded for parallelism: BM=32, BN=64, BK=64 -> grid (16,8) = 128 blocks
// (was 64: half the chip idle + 16-step serial chain). 8 K-steps, 12 KB LDS.
// 4 waves: wm = w&1 (16-row group), wn = w>>1 (32-col half), acc[2].
__global__ __launch_bounds__(256, 4) void nm_gemm(
    const __hip_bfloat16* __restrict__ A,   // 512x512 node bf16
    const __hip_bfloat16* __restrict__ W,   // 512x512 (o,h) bf16
    const float* __restrict__ bias,
    float* __restrict__ nm)
{
    __shared__ __align__(16) __hip_bfloat16 sA[32 * 64];   // 4 KB
    __shared__ __align__(16) __hip_bfloat16 sB[64 * 64];   // 8 KB
    int tid = threadIdx.x;
    int bm = blockIdx.x, bn = blockIdx.y;   // bm 0..15, bn 0..7
    int w = tid >> 6, l = tid & 63;
    int wm = w & 1, wn = w >> 1;
    int lq = l >> 4, lr = l & 15;

    const char* aBase = (const char*)A + (size_t)bm * 32 * 1024;  // row 1024B
    const char* bBase = (const char*)W + (size_t)bn * 64 * 1024;
    // A tile 32 rows x 128 B = 256 chunks (1/thread); B 64 rows = 512 (2/thread).
    // Source column pre-swizzled (c16 ^ row&7), LDS dest linear (rule #21).
    int rowA = tid >> 3;
    int gA = rowA * 1024 + (((tid & 7) ^ (rowA & 7)) << 4);
    int lO = tid * 16;
    int sw = lr & 7;

    f32x4 acc[2] = {};

    for (int kt = 0; kt < 8; ++kt) {
        int ko = kt * 128;
        cp16(aBase + gA + ko, (char*)sA + lO);
        cp16(bBase + gA + ko, (char*)sB + lO);            // B rows 0..31
        cp16(bBase + gA + 32768 + ko, (char*)sB + lO + 4096); // B rows 32..63
        __syncthreads();
#pragma unroll
        for (int kk = 0; kk < 2; ++kk) {
            bf16x8 af = *(const bf16x8*)&sA[(wm * 16 + lr) * 64 + (((kk * 4 + lq) ^ sw) << 3)];
#pragma unroll
            for (int ni = 0; ni < 2; ++ni) {
                bf16x8 bv = *(const bf16x8*)&sB[(wn * 32 + ni * 16 + lr) * 64 + (((kk * 4 + lq) ^ sw) << 3)];
                acc[ni] = __builtin_amdgcn_mfma_f32_16x16x32_bf16(af, bv, acc[ni], 0, 0, 0);
            }
        }
        __syncthreads();
    }
#pragma unroll
    for (int ni = 0; ni < 2; ++ni) {
        int col = bn * 64 + wn * 32 + ni * 16 + lr;
        float bv = bias[col];
#pragma unroll
        for (int r = 0; r < 4; ++r) {
            int row = bm * 32 + wm * 16 + lq * 4 + r;
            nm[(size_t)row * 512 + col] = acc[ni][r] + bv;
        }
    }
}

// ---------------------------------------------------------------------------
// t=0: es = lrelu(nm_i + nm_j + em0_b), write es, agg -> fused node update
__global__ __launch_bounds__(256) void edge_rank1(
    const float* __restrict__ nm, const float* __restrict__ em0,
    const int* __restrict__ mask,
    __hip_bfloat16* __restrict__ es_dst,
    const float* __restrict__ denom,
    float* __restrict__ nodef, __hip_bfloat16* __restrict__ nodeb)
{
    int g = blockIdx.x >> 1, ch = blockIdx.x & 1;
    int w = threadIdx.x >> 6, l = threadIdx.x & 63;
    int c = ch * 256 + w * 64 + l;
    int b = g >> 6;
    float nmi = nm[(size_t)g * 512 + c];          // raw nm[g][c]
    float emb = em0[b * 512 + c];
    const float* nmb = nm + (size_t)b * 64 * 512;
    const int* mrow = mask + g * 64;
    __hip_bfloat16* erow = es_dst + (size_t)g * 64 * 512 + c;
    float aggv = 0.f;
#pragma unroll 4
    for (int j = 0; j < 64; ++j) {
        float nmj = nmb[j * 512 + c];
        float es = lrelu(nmi + nmj + emb);
        erow[(size_t)j * 512] = __float2bfloat16(es);
        aggv += es * nmj * (float)mrow[j];
    }
    // fused node update (thread owns (g,c))
    float nf = (nmi + aggv) / denom[g];
    size_t idx = (size_t)g * 512 + c;
    float ns = nodef[idx] + lrelu(nf);
    nodef[idx] = ns;
    nodeb[idx] = __float2bfloat16(ns);
}

// ---------------------------------------------------------------------------
// Fused edge GEMM + epilogue + node update for t>=1.  BM=BN=128, BK=64.
// Round-0 structure (empirically best: single-buffered, 2x __syncthreads/kt)
// + __launch_bounds__(256,4): VGPR cap 128 -> 4 blocks/CU (LDS 32 KB allows
// 5). All 4 rounds show perf tracks resident blocks/CU (latency regime,
// m114 TLP mechanism) — this is the occupancy lever, nothing else changed.
__global__ __launch_bounds__(256, 4) void edge_fused(
    const __hip_bfloat16* __restrict__ es_src,   // 32768 x 512 bf16
    const __hip_bfloat16* __restrict__ eW,       // 512 x 512 bf16 (o,h)
    const float* __restrict__ eB,                // 512 fp32
    const float* __restrict__ nm,                // 512 x 512 fp32
    const int* __restrict__ mask,                // 8*64*64
    __hip_bfloat16* __restrict__ es_dst,
    const float* __restrict__ denom,
    float* __restrict__ nodef, __hip_bfloat16* __restrict__ nodeb,
    int write_es)
{
    __shared__ __align__(16) __hip_bfloat16 sA[128 * 64];   // 16 KB
    __shared__ __align__(16) __hip_bfloat16 sB[128 * 64];   // 16 KB
    int tid = threadIdx.x;
    // XCD swizzle: 4 bn-siblings of one A-tile land on one XCD's L2.
    int lid = blockIdx.y * 4 + blockIdx.x;
    int xcd = lid & 7, idx = lid >> 3;
    int bm = xcd + ((idx >> 2) << 3);            // 0..255
    int bn = idx & 3;                            // 0..3
    int w = tid >> 6, l = tid & 63;
    int wm = w >> 1, wn = w & 1;
    int lq = l >> 4, lr = l & 15;

    const char* aBase = (const char*)es_src + (size_t)bm * 128 * 1024;  // row 1024B
    const char* bBase = (const char*)eW + (size_t)bn * 128 * 1024;
    // staging: chunk c: row = c>>3, c16 = c&7; source column pre-swizzled
    // (c16 ^ row&7), LDS dest linear (rule #21); reads apply the same XOR.
    int rrow = tid >> 3;
    int gOff = rrow * 1024 + ((((tid & 7) ^ (rrow & 7))) << 4);
    int lOff = tid * 16;
    int sw = lr & 7;

    f32x4 acc[4][4] = {};

    for (int kt = 0; kt < 8; ++kt) {
        int ko = kt * 128;   // 64 cols * 2B
#pragma unroll
        for (int i = 0; i < 4; ++i) {
            cp16(aBase + gOff + i * 32768 + ko, (char*)sA + lOff + i * 4096);
            cp16(bBase + gOff + i * 32768 + ko, (char*)sB + lOff + i * 4096);
        }
        __syncthreads();
#pragma unroll
        for (int kk = 0; kk < 2; ++kk) {
            bf16x8 af[4], bfv[4];
#pragma unroll
            for (int mi = 0; mi < 4; ++mi)
                af[mi] = *(const bf16x8*)&sA[(wm * 64 + mi * 16 + lr) * 64 + (((kk * 4 + lq) ^ sw) << 3)];
#pragma unroll
            for (int ni = 0; ni < 4; ++ni)
                bfv[ni] = *(const bf16x8*)&sB[(wn * 64 + ni * 16 + lr) * 64 + (((kk * 4 + lq) ^ sw) << 3)];
#pragma unroll
            for (int mi = 0; mi < 4; ++mi)
#pragma unroll
                for (int ni = 0; ni < 4; ++ni)
                    acc[mi][ni] = __builtin_amdgcn_mfma_f32_16x16x32_bf16(af[mi], bfv[ni], acc[mi][ni], 0, 0, 0);
        }
        __syncthreads();
    }

    // Epilogue: wave owns group g = bm*2+wm (all 64 j) x 64 cols
    int g = bm * 2 + wm;            // = b*64 + i
    int b = g >> 6;
    int cbase = bn * 128 + wn * 64;

    float nmraw[4], nmi[4];
#pragma unroll
    for (int ni = 0; ni < 4; ++ni) {
        int c = cbase + ni * 16 + lr;
        nmraw[ni] = nm[(size_t)g * 512 + c];
        nmi[ni] = nmraw[ni] + eB[c];
    }
    const float* nmb = nm + (size_t)b * 64 * 512;
    const int* mrow = mask + g * 64;
    float aggv[4] = {0.f, 0.f, 0.f, 0.f};

#pragma unroll
    for (int mi = 0; mi < 4; ++mi) {
#pragma unroll
        for (int r = 0; r < 4; ++r) {
            int j = mi * 16 + lq * 4 + r;
            float mf = (float)mrow[j];
            const float* nrow = nmb + (size_t)j * 512;
            size_t erow = ((size_t)(g * 64 + j)) * 512;
#pragma unroll
            for (int ni = 0; ni < 4; ++ni) {
                int c = cbase + ni * 16 + lr;
                float nmj = nrow[c];
                float es = lrelu(acc[mi][ni][r] + nmi[ni] + nmj);
                if (write_es) es_dst[erow + c] = __float2bfloat16(es);
                aggv[ni] += es * nmj * mf;
            }
        }
    }
    float dinv = denom[g];
#pragma unroll
    for (int ni = 0; ni < 4; ++ni) {
        float v = aggv[ni];
        v += __shfl_xor(v, 16, 64);
        v += __shfl_xor(v, 32, 64);
        if (lq == 0) {
            size_t oidx = (size_t)g * 512 + cbase + ni * 16 + lr;
            float nf = (nmraw[ni] + v) / dinv;
            float ns = nodef[oidx] + lrelu(nf);
            nodef[oidx] = ns;
            nodeb[oidx] = __float2bfloat16(ns);
        }
    }
}

// ---------------------------------------------------------------------------
// out (fp32): out[b,i,j,0:512]=node[b,i,:], [512:1024]=node[b,j,:]
__global__ __launch_bounds__(256) void out_kernel(
    const float* __restrict__ nodef, float* __restrict__ out)
{
    size_t ch = (size_t)blockIdx.x * 256 + threadIdx.x;  // 16B chunk id
    int c4 = (int)(ch & 255);          // 256 chunks per 1024-float row
    size_t r = ch >> 8;                // (b*64+i)*64 + j
    int b = (int)(r >> 12);
    int i = (int)((r >> 6) & 63);
    int j = (int)(r & 63);
    int c = c4 * 4;
    const float* src = (c < 512) ? (nodef + ((size_t)(b * 64 + i)) * 512 + c)
                                 : (nodef + ((size_t)(b * 64 + j)) * 512 + (c - 512));
    *reinterpret_cast<float4*>(out + ch * 4) = *reinterpret_cast<const float4*>(src);
}

// ---------------------------------------------------------------------------
extern "C" void kernel_launch(void* const* d_in, const int* in_sizes, int n_in,
                              void* d_out, int out_size, void* d_ws, size_t ws_size,
                              hipStream_t stream) {
    const float* roi  = (const float*)d_in[0];
    const float* img  = (const float*)d_in[1];
    const float* nW   = (const float*)d_in[2];
    const float* nB   = (const float*)d_in[3];
    const float* eW   = (const float*)d_in[4];
    const float* eB   = (const float*)d_in[5];
    const int*   mask = (const int*)d_in[6];

    // Large scratch inside d_out (128 MB); all dead before out_kernel rewrites.
    char* ob = (char*)d_out;
    const size_t ES_BYTES = (size_t)32768 * 512 * 2;            // 33,554,432
    __hip_bfloat16* es0   = (__hip_bfloat16*)(ob);
    __hip_bfloat16* es1   = (__hip_bfloat16*)(ob + ES_BYTES);
    __hip_bfloat16* eWb   = (__hip_bfloat16*)(ob + 2 * ES_BYTES);              // 2.62MB
    __hip_bfloat16* nWb   = (__hip_bfloat16*)(ob + 2 * ES_BYTES + 2621440);    // 2.62MB
    __hip_bfloat16* nodeb = (__hip_bfloat16*)(ob + 2 * ES_BYTES + 5242880);    // 0.5MB
    float*          nm    = (float*)(ob + 2 * ES_BYTES + 5767168);             // 1MB
    float*       edge_init= (float*)(ob + 2 * ES_BYTES + 6815744);             // 16KB
    float*          em0   = (float*)(ob + 2 * ES_BYTES + 6832128);             // 16KB

    char* ws = (char*)d_ws;
    float* nodef = (float*)(ws);                 // 1MB
    float* denom = (float*)(ws + 1048576);       // 2KB
    float* outp  = (float*)d_out;

    prep_kernel<<<3842, 256, 0, stream>>>(roi, img, nW, eW, mask,
                                          nWb, eWb, nodef, nodeb, edge_init, denom);
    em0_kernel<<<1024, 256, 0, stream>>>(edge_init, eW, eB, em0);

    // t = 0
    nm_gemm<<<dim3(16, 8), 256, 0, stream>>>(nodeb, nWb, nB, nm);
    edge_rank1<<<1024, 256, 0, stream>>>(nm, em0, mask, es0, denom, nodef, nodeb);

    // t = 1..4
    for (int t = 1; t < NLAYER; ++t) {
        const __hip_bfloat16* src = (t & 1) ? es0 : es1;
        __hip_bfloat16* dst       = (t & 1) ? es1 : es0;
        nm_gemm<<<dim3(16, 8), 256, 0, stream>>>(nodeb, nWb + (size_t)t * 262144,
                                                 nB + t * 512, nm);
        edge_fused<<<dim3(4, 256), 256, 0, stream>>>(src, eWb + (size_t)t * 262144,
                                                     eB + t * 512, nm, mask,
                                                     dst, denom, nodef, nodeb,
                                                     (t < 4) ? 1 : 0);
    }

    out_kernel<<<32768, 256, 0, stream>>>(nodef, outp);
}